// Round 2
// baseline (1813.947 us; speedup 1.0000x reference)
//
#include <hip/hip_runtime.h>
#include <stdint.h>

typedef __attribute__((ext_vector_type(4))) float floatx4;
typedef __bf16 bf16x8 __attribute__((ext_vector_type(8)));
typedef unsigned short ushort_t;

// float -> bf16 round-to-nearest-even (raw bits)
__device__ __forceinline__ ushort_t f2bf(float f) {
  unsigned u = __float_as_uint(f);
  u += 0x7FFFu + ((u >> 16) & 1u);
  return (ushort_t)(u >> 16);
}

// async global->LDS, 16B per lane. LDS dest is wave-uniform base + lane*16.
__device__ __forceinline__ void gl_lds16(const void* g, void* l) {
  __builtin_amdgcn_global_load_lds(
      (__attribute__((address_space(1))) void*)g,
      (__attribute__((address_space(3))) void*)l, 16, 0, 0);
}

// raw barrier WITHOUT waitcnt drain (asm memory clobber = compiler fence for
// LDS code motion; HW waitcnts for ds_read deps are compiler-inserted since
// fragment loads are plain C++ derefs).
#define BAR() asm volatile("s_barrier" ::: "memory")
#define VM0() asm volatile("s_waitcnt vmcnt(0)" ::: "memory")

// ---------------- fp32 -> bf16 conversion (vectorized) ----------------
__global__ void cvt_f32_bf16(const float* __restrict__ src,
                             ushort_t* __restrict__ dst, long n) {
  long i = ((long)blockIdx.x * 256 + threadIdx.x) * 4;
  if (i >= n) return;
  float4 v = *(const float4*)(src + i);
  ushort4 o;
  o.x = f2bf(v.x); o.y = f2bf(v.y); o.z = f2bf(v.z); o.w = f2bf(v.w);
  *(ushort4*)(dst + i) = o;
}

// ---------------- bf16 GEMM, C = alpha * A * B^T (+bias) ----------------
// 256x256 tile, BK=64, 512 thr = 2(M)x4(N) waves, per-wave 128x64 output.
// Double-buffered LDS (128 KiB), 4 interleaved phases per K-tile:
//   ph0: read frags Q(0,0) | stage next A -> other buf | BAR | 16 MFMA | BAR
//   ph1: read B  Q(0,1)    | stage next B -> other buf | BAR | 16 MFMA | BAR
//   ph2: read A  Q(1,1)    |                             BAR | 16 MFMA | BAR
//   ph3: read B  Q(1,0)    |                 BAR | 16 MFMA | vmcnt(0) | BAR
// Race-free: stage targets the buffer whose reads ended at the previous
// iteration's final barrier; vmcnt(0) lands ~2 phases after last issue.
// LDS swizzle (T2): linear gl_lds dest + inverse-swizzled GLOBAL source
// (colblk ^= row&7) + same XOR on ds_read address (rule #21 involution).
// MODE 0: fp32 C[r*ldc+c]  = alpha*acc        (z-strided)
// MODE 3: fp32 C[r*ldc+c]  = acc + bias[c]
// MODE 4: fp32 C[r*ldc+c] += alpha*acc        (z-strided)
// MODE 5: fused QKV routing, QS=strideC elements per slab:
//         c<2048:  C[r*2048+c]                      (Q [b][n][d])
//         c<4096:  C[QS + r*2048 + (c-2048)]        (K [b][n][d])
//         else:    C[2*QS + (r>>11)*4194304 + (c-4096)*2048 + (r&2047)] (V^T)
template <int MODE>
__global__ __launch_bounds__(512, 2) void gemm256(
    const ushort_t* __restrict__ Abase, const ushort_t* __restrict__ Bbase,
    void* __restrict__ Cbase, const float* __restrict__ bias,
    int K, int lda, int ldb, int ldc,
    long strideA, long strideB, long strideC, float alpha) {
  __shared__ alignas(16) ushort_t sAB[2][2][256 * 64];

  const int z = blockIdx.z;
  const ushort_t* A = Abase + (long)z * strideA;
  const ushort_t* B = Bbase + (long)z * strideB;

  // bijective XCD swizzle (m204): contiguous chunk of flat ids per XCD.
  int bx, by;
  {
    const int gx = gridDim.x;
    const int nwg = gx * gridDim.y;
    const int f = blockIdx.x + gx * blockIdx.y;
    const int q = nwg >> 3, r = nwg & 7;
    const int xcd = f & 7, idx = f >> 3;
    const int fs = (xcd < r ? xcd * (q + 1) : r * (q + 1) + (xcd - r) * q) + idx;
    bx = fs % gx;
    by = fs / gx;
  }
  const int row0 = by * 256;  // M
  const int col0 = bx * 256;  // N

  const int tid  = threadIdx.x;
  const int lane = tid & 63;
  const int wave = tid >> 6;  // 0..7
  const int wm   = wave >> 2; // 0..1
  const int wn   = wave & 3;  // 0..3

  const int fr = lane & 15;   // row-in-16 for fragment reads
  const int kq = lane >> 4;   // k-octet 0..3

  // staging geometry: per gl_lds issue, thread t -> row (t>>3), colblk (t&7).
  // Pre-swizzle the GLOBAL column block so linear LDS holds swizzled layout.
  const int srow = lane >> 3;                 // row&7 of this lane's slice
  const int scol = ((lane & 7) ^ srow) * 8;   // inverse-swizzled col (elems)

  // ds_read swizzled column offsets (elements), ks = k-sub (0: k0..31, 1: k32..63)
  const int kx0 = ((kq << 3)) ^ ((fr & 7) << 3);
  const int kx1 = ((1 << 5) | (kq << 3)) ^ ((fr & 7) << 3);

  // per-thread global staging bases (row wave*8+srow, col scol)
  const ushort_t* Ag = A + (long)(row0 + wave * 8 + srow) * lda + scol;
  const ushort_t* Bg = B + (long)(col0 + wave * 8 + srow) * ldb + scol;

  const floatx4 zero4 = {0.f, 0.f, 0.f, 0.f};
  floatx4 acc[8][4];
#pragma unroll
  for (int a = 0; a < 8; ++a)
#pragma unroll
    for (int b = 0; b < 4; ++b) acc[a][b] = zero4;

  const int nt = K >> 6;  // K-tiles of 64

  auto stageA = [&](long kk, int buf) {
#pragma unroll
    for (int i = 0; i < 4; ++i)
      gl_lds16(Ag + (long)i * 64 * lda + kk,
               &sAB[buf][0][(i * 64 + wave * 8) * 64]);
  };
  auto stageB = [&](long kk, int buf) {
#pragma unroll
    for (int i = 0; i < 4; ++i)
      gl_lds16(Bg + (long)i * 64 * ldb + kk,
               &sAB[buf][1][(i * 64 + wave * 8) * 64]);
  };

  // prologue: stage tile 0 into buf 0
  stageA(0, 0);
  stageB(0, 0);
  VM0();
  BAR();

#define MFMA_Q(QM, QN)                                                       \
  _Pragma("unroll") for (int mi = 0; mi < 4; ++mi)                           \
  _Pragma("unroll") for (int nj = 0; nj < 2; ++nj)                           \
  _Pragma("unroll") for (int ks = 0; ks < 2; ++ks)                           \
      acc[(QM)*4 + mi][(QN)*2 + nj] = __builtin_amdgcn_mfma_f32_16x16x32_bf16( \
          af[mi][ks], bq[nj][ks], acc[(QM)*4 + mi][(QN)*2 + nj], 0, 0, 0);

  int cur = 0;
  for (int t = 0; t < nt; ++t) {
    const int nxt = cur ^ 1;
    const bool pf = (t + 1 < nt);
    const long kk = (long)(t + 1) << 6;
    const ushort_t* sA = sAB[cur][0];
    const ushort_t* sB = sAB[cur][1];
    bf16x8 af[4][2], bq[2][2];

    // ---- phase 0: quadrant (0,0) — fresh A(qm=0), fresh B(qn=0)
#pragma unroll
    for (int mi = 0; mi < 4; ++mi) {
      const int rowb = (wm * 128 + mi * 16 + fr) * 64;
      af[mi][0] = *(const bf16x8*)&sA[rowb + kx0];
      af[mi][1] = *(const bf16x8*)&sA[rowb + kx1];
    }
#pragma unroll
    for (int nj = 0; nj < 2; ++nj) {
      const int rowb = (wn * 64 + nj * 16 + fr) * 64;
      bq[nj][0] = *(const bf16x8*)&sB[rowb + kx0];
      bq[nj][1] = *(const bf16x8*)&sB[rowb + kx1];
    }
    if (pf) stageA(kk, nxt);
    BAR();
    __builtin_amdgcn_s_setprio(1);
    MFMA_Q(0, 0);
    __builtin_amdgcn_s_setprio(0);
    BAR();

    // ---- phase 1: quadrant (0,1) — reuse A, fresh B(qn=1)
#pragma unroll
    for (int nj = 0; nj < 2; ++nj) {
      const int rowb = (wn * 64 + 32 + nj * 16 + fr) * 64;
      bq[nj][0] = *(const bf16x8*)&sB[rowb + kx0];
      bq[nj][1] = *(const bf16x8*)&sB[rowb + kx1];
    }
    if (pf) stageB(kk, nxt);
    BAR();
    __builtin_amdgcn_s_setprio(1);
    MFMA_Q(0, 1);
    __builtin_amdgcn_s_setprio(0);
    BAR();

    // ---- phase 2: quadrant (1,1) — fresh A(qm=1), reuse B
#pragma unroll
    for (int mi = 0; mi < 4; ++mi) {
      const int rowb = (wm * 128 + 64 + mi * 16 + fr) * 64;
      af[mi][0] = *(const bf16x8*)&sA[rowb + kx0];
      af[mi][1] = *(const bf16x8*)&sA[rowb + kx1];
    }
    BAR();
    __builtin_amdgcn_s_setprio(1);
    MFMA_Q(1, 1);
    __builtin_amdgcn_s_setprio(0);
    BAR();

    // ---- phase 3: quadrant (1,0) — reuse A, fresh B(qn=0)
#pragma unroll
    for (int nj = 0; nj < 2; ++nj) {
      const int rowb = (wn * 64 + nj * 16 + fr) * 64;
      bq[nj][0] = *(const bf16x8*)&sB[rowb + kx0];
      bq[nj][1] = *(const bf16x8*)&sB[rowb + kx1];
    }
    BAR();
    __builtin_amdgcn_s_setprio(1);
    MFMA_Q(1, 0);
    __builtin_amdgcn_s_setprio(0);
    VM0();  // next tile fully landed; issued >= 2 phases ago
    BAR();

    cur = nxt;
  }
#undef MFMA_Q

  // C/D layout: col = lane&15, row = (lane>>4)*4 + reg   [verified m89/m91]
  const int ccol  = lane & 15;
  const int crow4 = (lane >> 4) * 4;

  if (MODE == 0 || MODE == 3 || MODE == 4) {
    float* C = (float*)Cbase + (long)z * strideC;
#pragma unroll
    for (int a = 0; a < 8; ++a) {
      const int rbase = row0 + wm * 128 + (a >> 2) * 64 + (a & 3) * 16 + crow4;
#pragma unroll
      for (int b = 0; b < 4; ++b) {
        const int c = col0 + wn * 64 + (b >> 1) * 32 + (b & 1) * 16 + ccol;
        const float bb = (MODE == 3) ? bias[c] : 0.f;
#pragma unroll
        for (int r = 0; r < 4; ++r) {
          const long idx = (long)(rbase + r) * ldc + c;
          float v;
          if (MODE == 3)      v = acc[a][b][r] + bb;
          else if (MODE == 4) v = C[idx] + alpha * acc[a][b][r];
          else                v = alpha * acc[a][b][r];
          C[idx] = v;
        }
      }
    }
  } else {  // MODE 5
    ushort_t* C = (ushort_t*)Cbase;
    const long QS = strideC;
#pragma unroll
    for (int a = 0; a < 8; ++a) {
      const int rbase = row0 + wm * 128 + (a >> 2) * 64 + (a & 3) * 16 + crow4;
#pragma unroll
      for (int b = 0; b < 4; ++b) {
        const int c = col0 + wn * 64 + (b >> 1) * 32 + (b & 1) * 16 + ccol;
#pragma unroll
        for (int r = 0; r < 4; ++r) {
          const int rr = rbase + r;
          const ushort_t v = f2bf(acc[a][b][r]);
          if (c < 2048)
            C[(long)rr * 2048 + c] = v;
          else if (c < 4096)
            C[QS + (long)rr * 2048 + (c - 2048)] = v;
          else
            C[2 * QS + (long)(rr >> 11) * 4194304 + (long)(c - 4096) * 2048 +
              (rr & 2047)] = v;
        }
      }
    }
  }
}

// ---------------- online column softmax (over query axis n) ----------------
__global__ void softmax_cols(const float* __restrict__ Sbase,
                             ushort_t* __restrict__ wbase) {
  __shared__ float rmx[8][32], rsum[8][32];
  const long zoff = (long)blockIdx.y * 4194304;
  const int tx = threadIdx.x & 31;
  const int ty = threadIdx.x >> 5;
  const int m = blockIdx.x * 32 + tx;
  const float* Sm = Sbase + zoff + m;
  const int n0 = ty * 256;

  float mx = -3.0e38f, sum = 0.f;
#pragma unroll 4
  for (int n = n0; n < n0 + 256; ++n) {
    const float v = Sm[(long)n * 2048];
    if (v > mx) {
      sum = sum * __expf(mx - v) + 1.f;
      mx = v;
    } else {
      sum += __expf(v - mx);
    }
  }
  rmx[ty][tx] = mx;
  rsum[ty][tx] = sum;
  __syncthreads();
  float gm = rmx[0][tx];
#pragma unroll
  for (int s = 1; s < 8; ++s) gm = fmaxf(gm, rmx[s][tx]);
  float gs = 0.f;
#pragma unroll
  for (int s = 0; s < 8; ++s) gs += rsum[s][tx] * __expf(rmx[s][tx] - gm);
  const float inv = 1.f / gs;

  ushort_t* wm_ = wbase + zoff + m;
#pragma unroll 4
  for (int n = n0; n < n0 + 256; ++n)
    wm_[(long)n * 2048] = f2bf(__expf(Sm[(long)n * 2048] - gm) * inv);
}

extern "C" void kernel_launch(void* const* d_in, const int* in_sizes, int n_in,
                              void* d_out, int out_size, void* d_ws,
                              size_t ws_size, hipStream_t stream) {
  const float* x   = (const float*)d_in[0];
  const float* Wq  = (const float*)d_in[1];
  const float* Wk  = (const float*)d_in[2];
  const float* Wv  = (const float*)d_in[3];
  const float* fcw = (const float*)d_in[4];
  const float* fcb = (const float*)d_in[5];
  float* out = (float*)d_out;

  char* ws = (char*)d_ws;
  size_t off = 0;
  auto alloc = [&](size_t bytes) {
    char* p = ws + off;
    off += (bytes + 255) & ~(size_t)255;
    return p;
  };
  const long SL = 4194304L;  // 2048*2048 elements
  const dim3 blk(256);
  const dim3 blk512(512);
  const float scale = 0.022097086912079608f;  // 1/sqrt(2048)

  // persistent
  ushort_t* xb   = (ushort_t*)alloc(33554432);  // x bf16 [8192][2048]
  ushort_t* fcwb = (ushort_t*)alloc(8388608);   // fc_w bf16
  float* mean32 = out;                          // fp32 head-sum accumulator in d_out
  char* loop0 = ws + off;

  cvt_f32_bf16<<<16384, blk, 0, stream>>>(x, xb, 16777216L);
  cvt_f32_bf16<<<4096, blk, 0, stream>>>(fcw, fcwb, 4194304L);

  // Layout A (batched over all b) needs 234,881,024 bytes total.
  const bool big = ws_size >= 234881024ULL;

  if (big) {
    ushort_t* Wcat = (ushort_t*)alloc(25165824);   // [6144][2048] bf16
    ushort_t* Qh   = (ushort_t*)alloc(33554432);   // [4][2048][2048]
    ushort_t* Kh   = (ushort_t*)alloc(33554432);   // contiguous after Qh
    ushort_t* Vth  = (ushort_t*)alloc(33554432);   // [4][2048 d][2048 m]
    float*    S    = (float*)alloc(67108864);      // [4][2048][2048] fp32
    ushort_t* wc   = Qh;                           // overlay (Q dead post-scores)
    (void)Kh; (void)Vth;

    for (int h = 0; h < 3; ++h) {
      cvt_f32_bf16<<<4096, blk, 0, stream>>>(Wq + h * SL, Wcat, SL);
      cvt_f32_bf16<<<4096, blk, 0, stream>>>(Wk + h * SL, Wcat + SL, SL);
      cvt_f32_bf16<<<4096, blk, 0, stream>>>(Wv + h * SL, Wcat + 2 * SL, SL);

      // fused QKV projection: M=8192, N=6144; QS slab = 16777216 elements
      gemm256<5><<<dim3(24, 32), blk512, 0, stream>>>(
          xb, Wcat, Qh, nullptr, 2048, 2048, 2048, 2048,
          0L, 0L, 16777216L, 1.0f);
      // scores, batched z=b
      gemm256<0><<<dim3(8, 8, 4), blk512, 0, stream>>>(
          Qh, Qh + 16777216L, S, nullptr, 2048, 2048, 2048, 2048,
          SL, SL, SL, scale);
      softmax_cols<<<dim3(64, 4), blk, 0, stream>>>(S, wc);
      // mean32[b] (+)= (1/3) * wc[b] @ Vth[b]^T
      if (h == 0)
        gemm256<0><<<dim3(8, 8, 4), blk512, 0, stream>>>(
            wc, Qh + 33554432L, mean32, nullptr, 2048, 2048, 2048, 2048,
            SL, SL, SL, 1.0f / 3.0f);
      else
        gemm256<4><<<dim3(8, 8, 4), blk512, 0, stream>>>(
            wc, Qh + 33554432L, mean32, nullptr, 2048, 2048, 2048, 2048,
            SL, SL, SL, 1.0f / 3.0f);
    }
  } else {
    // compact: exact round-3 footprint (109,051,904 bytes; proven safe)
    ushort_t* Wqh  = (ushort_t*)alloc(8388608);  // [2048][2048] -+
    ushort_t* Wkh  = (ushort_t*)alloc(8388608);  //               | contiguous
    ushort_t* Wvh  = (ushort_t*)alloc(8388608);  //              -+ = [6144][2048]
    ushort_t* Qhb  = (ushort_t*)alloc(8388608);  // [2048][2048] -+
    ushort_t* Khb  = (ushort_t*)alloc(8388608);  //               | contiguous
    ushort_t* Vthb = (ushort_t*)alloc(8388608);  //              -+
    float*    S    = (float*)alloc(16777216);    // [2048][2048] fp32
    ushort_t* wchb = Qhb;                        // overlay
    (void)Wkh; (void)Wvh; (void)Khb; (void)Vthb;

    for (int h = 0; h < 3; ++h) {
      cvt_f32_bf16<<<4096, blk, 0, stream>>>(Wq + h * SL, Wqh, SL);
      cvt_f32_bf16<<<4096, blk, 0, stream>>>(Wk + h * SL, Wqh + SL, SL);
      cvt_f32_bf16<<<4096, blk, 0, stream>>>(Wv + h * SL, Wqh + 2 * SL, SL);

      for (int b = 0; b < 4; ++b) {
        const ushort_t* xbb = xb + b * SL;
        // fused QKV projection: M=2048, N=6144; QS slab = 4194304 elements
        gemm256<5><<<dim3(24, 8), blk512, 0, stream>>>(
            xbb, Wqh, Qhb, nullptr, 2048, 2048, 2048, 2048,
            0L, 0L, 4194304L, 1.0f);
        gemm256<0><<<dim3(8, 8), blk512, 0, stream>>>(
            Qhb, Qhb + SL, S, nullptr, 2048, 2048, 2048, 2048,
            0L, 0L, 0L, scale);
        softmax_cols<<<dim3(64, 1), blk, 0, stream>>>(S, wchb);
        if (h == 0)
          gemm256<0><<<dim3(8, 8), blk512, 0, stream>>>(
              wchb, Qhb + 2 * SL, mean32 + b * SL, nullptr, 2048,
              2048, 2048, 2048, 0L, 0L, 0L, 1.0f / 3.0f);
        else
          gemm256<4><<<dim3(8, 8), blk512, 0, stream>>>(
              wchb, Qhb + 2 * SL, mean32 + b * SL, nullptr, 2048,
              2048, 2048, 2048, 0L, 0L, 0L, 1.0f / 3.0f);
      }
    }
  }

  // mean (in d_out) -> bf16 overlay in loop region, then out = mean@fc_w^T + fc_b
  ushort_t* meanb = (ushort_t*)loop0;
  cvt_f32_bf16<<<16384, blk, 0, stream>>>(mean32, meanb, 16777216L);
  gemm256<3><<<dim3(8, 32), blk512, 0, stream>>>(
      meanb, fcwb, out, fcb, 2048, 2048, 2048, 2048,
      0L, 0L, 0L, 1.0f);
}